// Round 3
// baseline (23252.122 us; speedup 1.0000x reference)
//
#include <hip/hip_runtime.h>
#include <hip/hip_bf16.h>
#include <stdint.h>

#define TSTEPS 512
#define BATCH  256
#define EDIM   512
#define HDIM   1024

typedef __attribute__((ext_vector_type(8))) short bfx8;
typedef __attribute__((ext_vector_type(4))) float f32x4;
typedef __attribute__((ext_vector_type(4))) unsigned short u16x4;

__device__ __forceinline__ unsigned short f2bf(float f) {
    union { float f; unsigned int u; } v; v.f = f;
    unsigned int r = v.u + 0x7fffu + ((v.u >> 16) & 1u);
    return (unsigned short)(r >> 16);
}

// ---------------- init: zero the per-group step counters ----------------
__global__ void k_init(int* __restrict__ cnt) {
    int i = blockIdx.x * blockDim.x + threadIdx.x;
    if (i < 16 * TSTEPS) cnt[i] = 0;
}

// ---------------- Wxh -> Wt (transposed, bf16) [HDIM][EDIM] ----------------
__global__ void k_wt(const float* __restrict__ Wxh, unsigned short* __restrict__ Wt) {
    int k = blockIdx.x;                       // 0..511 (E rows)
    const float* row = Wxh + (size_t)k * HDIM;
    for (int c = threadIdx.x; c < HDIM; c += blockDim.x)
        Wt[(size_t)c * EDIM + k] = f2bf(row[c]);
}

// ---------------- phase 1: out = x @ Wxh + bxh (fp32 out = xh) ----------------
// 128x128 tile, BK=64, 4 waves (2x2), bf16 MFMA 16x16x32, XOR-swizzled LDS.
__launch_bounds__(256, 2)
__global__ void k_xh(const float* __restrict__ x, const unsigned short* __restrict__ Wt,
                     const float* __restrict__ bxh, float* __restrict__ out) {
    __shared__ unsigned short As[128 * 64];   // [row][k] swizzled
    __shared__ unsigned short Bs[128 * 64];   // [col][k] swizzled

    int bid = blockIdx.x;
    // XCD-grouping: all 8 nb-blocks of one mb land on the same XCD (bid%8 == mb%8)
    int mb = (bid >> 6) * 8 + (bid & 7);      // 0..1023
    int nb = (bid >> 3) & 7;                  // 0..7
    int tid = threadIdx.x;
    int lane = tid & 63;
    int w = tid >> 6;
    int wr = w >> 1, wc = w & 1;

    f32x4 acc[4][4] = {};
    int srow = tid >> 1, shalf = tid & 1;     // staging: row 0..127, 32-elem half

    for (int kb = 0; kb < 8; ++kb) {
        // stage A (fp32 -> bf16): 32 floats per thread
        const float* ap = x + (size_t)(mb * 128 + srow) * EDIM + kb * 64 + shalf * 32;
        #pragma unroll
        for (int i = 0; i < 4; ++i) {
            f32x4 f0 = ((const f32x4*)ap)[2 * i];
            f32x4 f1 = ((const f32x4*)ap)[2 * i + 1];
            bfx8 b;
            b[0] = (short)f2bf(f0[0]); b[1] = (short)f2bf(f0[1]);
            b[2] = (short)f2bf(f0[2]); b[3] = (short)f2bf(f0[3]);
            b[4] = (short)f2bf(f1[0]); b[5] = (short)f2bf(f1[1]);
            b[6] = (short)f2bf(f1[2]); b[7] = (short)f2bf(f1[3]);
            int kcol = shalf * 32 + 8 * i;
            int byte = srow * 128 + kcol * 2; byte ^= (srow & 7) << 4;
            *(bfx8*)((char*)As + byte) = b;
        }
        // stage B (already bf16): 32 bf16 per thread  [R1 FIX: was i<2 -> half of Bs
        // never written; uninitialized LDS garbage -> inf through MFMA]
        const bfx8* bp = (const bfx8*)(Wt + (size_t)(nb * 128 + srow) * EDIM + kb * 64 + shalf * 32);
        #pragma unroll
        for (int i = 0; i < 4; ++i) {
            bfx8 b = bp[i];
            int kcol = shalf * 32 + 8 * i;
            int byte = srow * 128 + kcol * 2; byte ^= (srow & 7) << 4;
            *(bfx8*)((char*)Bs + byte) = b;
        }
        __syncthreads();
        #pragma unroll
        for (int kk = 0; kk < 2; ++kk) {
            bfx8 a[4], bb[4];
            int kcol = kk * 32 + (lane >> 4) * 8;
            #pragma unroll
            for (int m = 0; m < 4; ++m) {
                int row = wr * 64 + m * 16 + (lane & 15);
                int byte = row * 128 + kcol * 2; byte ^= (row & 7) << 4;
                a[m] = *(const bfx8*)((const char*)As + byte);
            }
            #pragma unroll
            for (int n = 0; n < 4; ++n) {
                int col = wc * 64 + n * 16 + (lane & 15);
                int byte = col * 128 + kcol * 2; byte ^= (col & 7) << 4;
                bb[n] = *(const bfx8*)((const char*)Bs + byte);
            }
            #pragma unroll
            for (int m = 0; m < 4; ++m)
                #pragma unroll
                for (int n = 0; n < 4; ++n)
                    acc[m][n] = __builtin_amdgcn_mfma_f32_16x16x32_bf16(a[m], bb[n], acc[m][n], 0, 0, 0);
        }
        __syncthreads();
    }
    // epilogue: + bias, store fp32
    int colbase = nb * 128 + wc * 64;
    float bias[4];
    #pragma unroll
    for (int n = 0; n < 4; ++n) bias[n] = bxh[colbase + n * 16 + (lane & 15)];
    #pragma unroll
    for (int m = 0; m < 4; ++m) {
        int row0 = mb * 128 + wr * 64 + m * 16 + (lane >> 4) * 4;
        #pragma unroll
        for (int n = 0; n < 4; ++n) {
            int col = colbase + n * 16 + (lane & 15);
            #pragma unroll
            for (int j = 0; j < 4; ++j)
                out[(size_t)(row0 + j) * HDIM + col] = acc[m][n][j] + bias[n];
        }
    }
}

// ---------------- phase 2: recurrent h_t = relu(xh_t + h_{t-1} @ Whh) ----------------
// 256 WGs = 16 batch-groups (16 rows) x 16 col-slices (64 cols). Whh slice in registers.
// Waves split K 4-ways; LDS reduce; per-group atomic-counter sync (agent scope).
__launch_bounds__(256, 1)
__global__ void k_rnn(const float* __restrict__ Whh, float* __restrict__ out,
                      unsigned short* __restrict__ hbuf, int* __restrict__ cnt) {
    __shared__ float smem[8192];              // 32KB: setup chunk buf / partials buf

    int bid = blockIdx.x;
    int xcd = bid & 7, slot = bid >> 3;
    int g  = xcd * 2 + (slot & 1);            // batch group 0..15 (16 WGs share an XCD)
    int hb = slot >> 1;                       // col slice 0..15
    int tid = threadIdx.x;
    int lane = tid & 63;
    int w = tid >> 6;                         // wave = K quarter
    int rb = g * 16;
    int cb = hb * 64;

    // ---- setup: Whh[:, cb..cb+64) k-quarter w -> registers (B-operand frags)
    bfx8 breg[8][4];
    unsigned short* bt = (unsigned short*)smem;   // [64 col][256 k] bf16 swizzled
    for (int c = 0; c < 4; ++c) {
        int col = tid & 63;
        int kb0 = (tid >> 6) * 64;
        #pragma unroll
        for (int jj = 0; jj < 8; ++jj) {
            bfx8 b;
            #pragma unroll
            for (int j = 0; j < 8; ++j) {
                int k = 256 * c + kb0 + 8 * jj + j;
                b[j] = (short)f2bf(Whh[(size_t)k * HDIM + cb + col]);
            }
            int byte = col * 512 + (kb0 + 8 * jj) * 2; byte ^= (col & 7) << 4;
            *(bfx8*)((char*)bt + byte) = b;
        }
        __syncthreads();
        if (w == c) {
            #pragma unroll
            for (int kk = 0; kk < 8; ++kk)
                #pragma unroll
                for (int n = 0; n < 4; ++n) {
                    int col2 = n * 16 + (lane & 15);
                    int kl = kk * 32 + (lane >> 4) * 8;
                    int byte = col2 * 512 + kl * 2; byte ^= (col2 & 7) << 4;
                    breg[kk][n] = *(const bfx8*)((const char*)bt + byte);
                }
        }
        __syncthreads();
    }

    const int PSTRIDE = BATCH * HDIM;         // 262144
    float* part = smem;                       // [4][16][64] f32
    int rr = tid >> 4;                        // reduce ownership: row 0..15
    int rc = (tid & 15) * 4;                  // 4 cols

    for (int t = 0; t < TSTEPS; ++t) {
        f32x4 acc[4] = {};
        if (t > 0) {
            if (tid == 0) {
                while (__hip_atomic_load(&cnt[g * TSTEPS + t - 1],
                                         __ATOMIC_ACQUIRE, __HIP_MEMORY_SCOPE_AGENT) < 16) {}
            }
            __syncthreads();
            __threadfence();
            const unsigned short* hp = hbuf + (size_t)((t - 1) & 1) * PSTRIDE
                                     + (size_t)(rb + (lane & 15)) * HDIM + w * 256 + (lane >> 4) * 8;
            #pragma unroll
            for (int kk = 0; kk < 8; ++kk) {
                bfx8 af = *(const bfx8*)(hp + kk * 32);
                #pragma unroll
                for (int n = 0; n < 4; ++n)
                    acc[n] = __builtin_amdgcn_mfma_f32_16x16x32_bf16(af, breg[kk][n], acc[n], 0, 0, 0);
            }
        }
        // partials -> LDS
        #pragma unroll
        for (int n = 0; n < 4; ++n) {
            int col = n * 16 + (lane & 15);
            int row = (lane >> 4) * 4;
            #pragma unroll
            for (int j = 0; j < 4; ++j)
                part[w * 1024 + (row + j) * 64 + col] = acc[n][j];
        }
        __syncthreads();
        // reduce + xh + relu; in-place overwrite xh with h_t; store bf16 h for next step
        float* op = out + ((size_t)(rb + rr) * TSTEPS + t) * HDIM + cb + rc;
        f32x4 s = *(const f32x4*)op;
        #pragma unroll
        for (int ww = 0; ww < 4; ++ww)
            s += *(const f32x4*)&part[ww * 1024 + rr * 64 + rc];
        #pragma unroll
        for (int j = 0; j < 4; ++j) s[j] = fmaxf(s[j], 0.0f);
        *(f32x4*)op = s;
        u16x4 hv;
        hv[0] = f2bf(s[0]); hv[1] = f2bf(s[1]); hv[2] = f2bf(s[2]); hv[3] = f2bf(s[3]);
        *(u16x4*)(hbuf + (size_t)(t & 1) * PSTRIDE + (size_t)(rb + rr) * HDIM + cb + rc) = hv;
        __threadfence();
        __syncthreads();
        if (tid == 0)
            __hip_atomic_fetch_add(&cnt[g * TSTEPS + t], 1,
                                   __ATOMIC_RELEASE, __HIP_MEMORY_SCOPE_AGENT);
    }
}

extern "C" void kernel_launch(void* const* d_in, const int* in_sizes, int n_in,
                              void* d_out, int out_size, void* d_ws, size_t ws_size,
                              hipStream_t stream) {
    const float* x   = (const float*)d_in[0];
    const float* Wxh = (const float*)d_in[1];
    const float* bxh = (const float*)d_in[2];
    const float* Whh = (const float*)d_in[3];
    float* out = (float*)d_out;

    // ws layout: hbuf (2 * 256*1024 bf16 = 1MB) | cnt (16*512 int = 32KB) | Wt (1MB)
    unsigned short* hbuf = (unsigned short*)d_ws;
    int* cnt = (int*)((char*)d_ws + (size_t)2 * BATCH * HDIM * 2);
    unsigned short* Wt = (unsigned short*)((char*)cnt + 16 * TSTEPS * sizeof(int));

    k_init<<<32, 256, 0, stream>>>(cnt);
    k_wt<<<EDIM, 256, 0, stream>>>(Wxh, Wt);
    k_xh<<<8192, 256, 0, stream>>>(x, Wt, bxh, out);
    k_rnn<<<256, 256, 0, stream>>>(Whh, out, hbuf, cnt);
}